// Round 17
// baseline (1080.272 us; speedup 1.0000x reference)
//
#include <hip/hip_runtime.h>

#define NB   16
#define NPC  4096
#define MPC  1024
#define KNB  64
#define FIN  64
#define CAP  448   // candidate capacity per centroid (mean ~137, +26 sigma)

typedef unsigned short u16;
typedef unsigned int   u32;
typedef unsigned long long u64;
typedef __attribute__((ext_vector_type(8))) short short8;
typedef __attribute__((ext_vector_type(4))) float f32x4;

__device__ __forceinline__ u16 f2bf(float f) {
  u32 u = __float_as_uint(f);
  u = u + 0x7fffu + ((u >> 16) & 1u);
  return (u16)(u >> 16);
}
__device__ __forceinline__ float bf2f(u16 b) {
  return __uint_as_float(((u32)b) << 16);
}
__device__ __forceinline__ u32 umax2(u32 a, u32 b) { return a > b ? a : b; }

// ---- DPP wave reduces (VALU pipe). bound_ctrl=false => invalid/masked
// lanes keep old; compiler inserts mandatory DPP hazard waits (raw asm
// faulted in R2). row_shr moves values toward HIGHER lanes (R3-verified).
#define DPP64_MAX(best, ctrl, rmask) do { \
  u32 _lo = (u32)(best), _hi = (u32)((best) >> 32); \
  u32 _olo = (u32)__builtin_amdgcn_update_dpp((int)_lo, (int)_lo, (ctrl), (rmask), 0xf, false); \
  u32 _ohi = (u32)__builtin_amdgcn_update_dpp((int)_hi, (int)_hi, (ctrl), (rmask), 0xf, false); \
  u64 _o = ((u64)_ohi << 32) | _olo; \
  (best) = _o > (best) ? _o : (best); \
} while (0)

__device__ __forceinline__ u32 wave_max_u32(u32 x) {
  u32 t;
  t = (u32)__builtin_amdgcn_update_dpp((int)x, (int)x, 0x111, 0xf, 0xf, false); x = x > t ? x : t;
  t = (u32)__builtin_amdgcn_update_dpp((int)x, (int)x, 0x112, 0xf, 0xf, false); x = x > t ? x : t;
  t = (u32)__builtin_amdgcn_update_dpp((int)x, (int)x, 0x114, 0xf, 0xf, false); x = x > t ? x : t;
  t = (u32)__builtin_amdgcn_update_dpp((int)x, (int)x, 0x118, 0xf, 0xf, false); x = x > t ? x : t;
  t = (u32)__builtin_amdgcn_update_dpp((int)x, (int)x, 0x142, 0xa, 0xf, false); x = x > t ? x : t;
  t = (u32)__builtin_amdgcn_update_dpp((int)x, (int)x, 0x143, 0xc, 0xf, false); x = x > t ? x : t;
  return x;
}

struct FpsLDS {
  float4 sxyz[NPC];     // packed coords (initial load + final flush)
  u64 swave[2][8];      // per-wave keys, parity-dbuf
  float4 scds[2][8];    // per-wave winner coords, parity-dbuf
  int sidx[MPC];
};
struct YLDS { float xs[64][68]; float ws[64][68]; };
union FusedLDS { FpsLDS f; YLDS g; char pad[86016]; };  // 84KB => 1 block/CU
                                                        // (fps CUs exclusive)

// ---------------------------------------------------------------- fused FPS + y + w2t
// Blocks 0..15: FPS (R16-proven structure + coords-through-scan).
//   Selection: 8 ballots + all-scalar first-r/ctz pick; the SAME cascade
//   also carries the winner's coords (lane ctz(msel) holds p[rsel] = the
//   wave winner). Owner lane writes them to scds[pr][w]; after the
//   barrier lanes 0-7 read keys AND coords in parallel, and the new
//   centroid's coords come from 3 v_readlane (winner wave = (last>>6)&7,
//   uniform) instead of a dependent sxyz[last] LDS fetch (~120 cyc off
//   the serial chain). Coords are register copies of original bits;
//   pos_out still gathers from sxyz[sidx] => bit-exact.
// Blocks 16..1039: y = x @ W1[:64]. Block 1040: W2 -> bf16 transposed.
__global__ __launch_bounds__(512)
void fused_kernel(const float* __restrict__ pos, const float* __restrict__ x,
                  const float* __restrict__ w1, const float* __restrict__ w2,
                  int* __restrict__ idx_out, float* __restrict__ pos_out,
                  float* __restrict__ batch_out, u16* __restrict__ y,
                  u16* __restrict__ w2t) {
  __shared__ FusedLDS L;
  const int bid = blockIdx.x;
  const int t = threadIdx.x;
  if (bid < NB) {
    const int b = bid;
    const int w = t >> 6, lane = t & 63;
    const float* P = pos + (size_t)b * NPC * 3;
    for (int i = t; i < NPC; i += 512)
      L.f.sxyz[i] = make_float4(P[3*i+0], P[3*i+1], P[3*i+2], 0.f);
    for (int i = t; i < MPC; i += 512) batch_out[b*MPC + i] = (float)b;
    if (t == 0) L.f.sidx[0] = 0;
    __syncthreads();
    float px[8], py[8], pz[8], mind[8];
#pragma unroll
    for (int r = 0; r < 8; ++r) {
      float4 p = L.f.sxyz[t + (r << 9)];
      px[r] = p.x; py[r] = p.y; pz[r] = p.z;
      mind[r] = __builtin_inff();
    }
    // current centroid coords in registers (point 0 broadcast)
    float cx, cy, cz;
    {
      float4 c0 = L.f.sxyz[0];
      cx = c0.x; cy = c0.y; cz = c0.z;
    }
    int last = 0;
    for (int m = 1; m < MPC; ++m) {
      const int pr = m & 1;
#pragma unroll
      for (int r = 0; r < 8; ++r) {
        float dx = __fsub_rn(px[r], cx);
        float dy = __fsub_rn(py[r], cy);
        float dz = __fsub_rn(pz[r], cz);
        float d2 = __fadd_rn(__fadd_rn(__fmul_rn(dx,dx), __fmul_rn(dy,dy)), __fmul_rn(dz,dz));
        mind[r] = fminf(mind[r], d2);
      }
      u32 q0 = __float_as_uint(mind[0]), q1 = __float_as_uint(mind[1]);
      u32 q2 = __float_as_uint(mind[2]), q3 = __float_as_uint(mind[3]);
      u32 q4 = __float_as_uint(mind[4]), q5 = __float_as_uint(mind[5]);
      u32 q6 = __float_as_uint(mind[6]), q7 = __float_as_uint(mind[7]);
      u32 vmax = umax2(umax2(umax2(q0,q1), umax2(q2,q3)),
                       umax2(umax2(q4,q5), umax2(q6,q7)));
      vmax = wave_max_u32(vmax);
      u32 V = (u32)__builtin_amdgcn_readlane((int)vmax, 63);
      // --- scalar argmin-index selection (R14-proven) + coords carry
      u64 mk0 = __ballot(q0 == V);
      u64 mk1 = __ballot(q1 == V);
      u64 mk2 = __ballot(q2 == V);
      u64 mk3 = __ballot(q3 == V);
      u64 mk4 = __ballot(q4 == V);
      u64 mk5 = __ballot(q5 == V);
      u64 mk6 = __ballot(q6 == V);
      u64 mk7 = __ballot(q7 == V);
      u64 msel = mk7; u32 rsel = 7u;
      float ox = px[7], oy = py[7], oz = pz[7];
      msel = mk6 ? mk6 : msel; rsel = mk6 ? 6u : rsel;
      ox = mk6 ? px[6] : ox; oy = mk6 ? py[6] : oy; oz = mk6 ? pz[6] : oz;
      msel = mk5 ? mk5 : msel; rsel = mk5 ? 5u : rsel;
      ox = mk5 ? px[5] : ox; oy = mk5 ? py[5] : oy; oz = mk5 ? pz[5] : oz;
      msel = mk4 ? mk4 : msel; rsel = mk4 ? 4u : rsel;
      ox = mk4 ? px[4] : ox; oy = mk4 ? py[4] : oy; oz = mk4 ? pz[4] : oz;
      msel = mk3 ? mk3 : msel; rsel = mk3 ? 3u : rsel;
      ox = mk3 ? px[3] : ox; oy = mk3 ? py[3] : oy; oz = mk3 ? pz[3] : oz;
      msel = mk2 ? mk2 : msel; rsel = mk2 ? 2u : rsel;
      ox = mk2 ? px[2] : ox; oy = mk2 ? py[2] : oy; oz = mk2 ? pz[2] : oz;
      msel = mk1 ? mk1 : msel; rsel = mk1 ? 1u : rsel;
      ox = mk1 ? px[1] : ox; oy = mk1 ? py[1] : oy; oz = mk1 ? pz[1] : oz;
      msel = mk0 ? mk0 : msel; rsel = mk0 ? 0u : rsel;
      ox = mk0 ? px[0] : ox; oy = mk0 ? py[0] : oy; oz = mk0 ? pz[0] : oz;
      u32 ctzl = (u32)__builtin_ctzll(msel);
      u32 cand = (u32)(w << 6) + ctzl + (rsel << 9);
      if (lane == ctzl) L.f.scds[pr][w] = make_float4(ox, oy, oz, 0.f);
      if (lane == 63) L.f.swave[pr][w] = ((u64)V << 32) | (u32)(~cand);
      __syncthreads();   // single barrier per step (parity double-buffer)
      u64 sv = 0;
      float4 crd = make_float4(0.f, 0.f, 0.f, 0.f);
      if (lane < 8) {
        sv = L.f.swave[pr][lane];
        crd = L.f.scds[pr][lane];   // issues in parallel with the key read
      }
      DPP64_MAX(sv, 0x111, 0xf);
      DPP64_MAX(sv, 0x112, 0xf);
      DPP64_MAX(sv, 0x114, 0xf);
      u32 lo = (u32)__builtin_amdgcn_readlane((int)(u32)sv, 7);
      last = (int)(~lo);
      int wavewin = (last >> 6) & 7;   // uniform
      cx = __uint_as_float((u32)__builtin_amdgcn_readlane((int)__float_as_uint(crd.x), wavewin));
      cy = __uint_as_float((u32)__builtin_amdgcn_readlane((int)__float_as_uint(crd.y), wavewin));
      cz = __uint_as_float((u32)__builtin_amdgcn_readlane((int)__float_as_uint(crd.z), wavewin));
      if (t == 0) L.f.sidx[m] = last;  // LDS only — no vmem in the loop
    }
    __syncthreads();
    for (int i = t; i < MPC; i += 512) {
      int ii = L.f.sidx[i];
      idx_out[b*MPC + i] = ii;
      float4 p = L.f.sxyz[ii];
      size_t po = ((size_t)b*MPC + i)*3;
      pos_out[po+0] = p.x; pos_out[po+1] = p.y; pos_out[po+2] = p.z;
    }
  } else if (bid < NB + 1024) {
    const size_t row0 = (size_t)(bid - NB) * 64;
#pragma unroll
    for (int k = 0; k < 2; ++k) {
      int l4 = t + 512*k;              // 0..1023 float4 index
      int r = l4 >> 4, c4 = l4 & 15;
      *(float4*)&L.g.xs[r][c4*4] = *(const float4*)&x[(row0 + r)*64 + c4*4];
      *(float4*)&L.g.ws[r][c4*4] = *(const float4*)&w1[r*64 + c4*4];
    }
    __syncthreads();
    const int r = t >> 3, c0 = (t & 7) << 3;
    float acc[8];
#pragma unroll
    for (int i = 0; i < 8; ++i) acc[i] = 0.f;
    for (int k = 0; k < 64; ++k) {
      float a = L.g.xs[r][k];
      float4 w0 = *(const float4*)&L.g.ws[k][c0];
      float4 w1v = *(const float4*)&L.g.ws[k][c0 + 4];
      acc[0] += a * w0.x; acc[1] += a * w0.y; acc[2] += a * w0.z; acc[3] += a * w0.w;
      acc[4] += a * w1v.x; acc[5] += a * w1v.y; acc[6] += a * w1v.z; acc[7] += a * w1v.w;
    }
    u32 u[4];
#pragma unroll
    for (int i = 0; i < 4; ++i)
      u[i] = (u32)f2bf(acc[2*i]) | ((u32)f2bf(acc[2*i+1]) << 16);
    *(uint4*)(y + ((row0 + r)*64 + c0)) = make_uint4(u[0], u[1], u[2], u[3]);
  } else {
    for (int i = t; i < 64*128; i += 512) {
      int k = i >> 7, c = i & 127;
      w2t[c*64 + k] = f2bf(w2[i]);
    }
  }
}

// ---------------------------------------------------------------- radius + top-64 neighbors
// (verbatim R9/R14 — proven)
__global__ __launch_bounds__(256)
void nbr_kernel(const float* __restrict__ pos, const int* __restrict__ idx,
                int* __restrict__ nbr, int* __restrict__ nvalid) {
  const int bid = blockIdx.x;
  const int sw = (bid & 7) * 512 + (bid >> 3);   // bijective XCD swizzle (4096 = 8*512)
  const int cloud = sw >> 8;
  const int mbase = (sw & 255) << 2;
  __shared__ float sx[NPC], sy[NPC], sz[NPC];
  __shared__ u64 cand[4][CAP];
  const float* P = pos + (size_t)cloud * NPC * 3;
  const int t = threadIdx.x;
  for (int i = t; i < NPC; i += 256) { sx[i]=P[3*i]; sy[i]=P[3*i+1]; sz[i]=P[3*i+2]; }
  __syncthreads();
  const int wv = t >> 6, lane = t & 63;
  const int m = mbase + wv;
  const int g = cloud * MPC + m;
  const int ci = idx[g];
  const float cx = sx[ci], cy = sy[ci], cz = sz[ci];
  const float R2 = 0.04000000059604644775f;      // (float)(0.2*0.2)
  const u64 ltmask = (lane == 0) ? 0ull : (~0ull >> (64 - lane));
  int base = 0;
  for (int i = 0; i < NPC/64; ++i) {
    int j = (i << 6) + lane;
    float dx = __fsub_rn(cx, sx[j]);
    float dy = __fsub_rn(cy, sy[j]);
    float dz = __fsub_rn(cz, sz[j]);
    float d2 = __fadd_rn(__fadd_rn(__fmul_rn(dx,dx), __fmul_rn(dy,dy)), __fmul_rn(dz,dz));
    bool in = d2 <= R2;
    u64 mk = __ballot(in);
    if (in) {
      int slot = base + (int)__popcll(mk & ltmask);
      if (slot < CAP)
        cand[wv][slot] = ((u64)__float_as_uint(d2) << 32) | (u32)j;
    }
    base += (int)__popcll(mk);
  }
  int cnt = base < CAP ? base : CAP;
  u64 mykey[7];
  int myrank[7];
#pragma unroll
  for (int u = 0; u < 7; ++u) {
    int s = lane + (u << 6);
    mykey[u] = (s < cnt) ? cand[wv][s] : ~0ull;
    myrank[u] = 0;
  }
  for (int jj = 0; jj < cnt; ++jj) {
    u64 kj = cand[wv][jj];
#pragma unroll
    for (int u = 0; u < 7; ++u) myrank[u] += (kj < mykey[u]) ? 1 : 0;
  }
#pragma unroll
  for (int u = 0; u < 7; ++u) {
    int s = lane + (u << 6);
    if (s < cnt && myrank[u] < KNB)
      nbr[(size_t)g*KNB + myrank[u]] = cloud*NPC + (int)(mykey[u] & 0xffffffffull);
  }
  if (lane == 0) nvalid[g] = cnt < KNB ? cnt : KNB;
}

// ---------------------------------------------------------------- PointNetConv (one block per centroid)
// (verbatim R9/R14 — proven)
__global__ __launch_bounds__(256)
void conv_kernel(const float* __restrict__ pos, const int* __restrict__ idx,
                 const int* __restrict__ nbr, const int* __restrict__ nvalid,
                 const u16* __restrict__ y, const u16* __restrict__ w2t,
                 const float* __restrict__ w1, const float* __restrict__ b1,
                 const float* __restrict__ b2, float* __restrict__ out) {
  const int bid = blockIdx.x;
  const int g = (bid & 7) * 2048 + (bid >> 3);   // bijective XCD swizzle (16384 = 8*2048)
  const int cloud = g >> 10;
  __shared__ u16 YH[64][72];     // y rows, then relu'd H1 in-place (same-thread RMW)
  __shared__ u16 WT[128][72];    // W2^T bf16
  __shared__ float rel[64][3];
  __shared__ int nbs[64];
  __shared__ float w1p[192];
  __shared__ float b1s[64];
  const int t = threadIdx.x;
  const int nv = nvalid[g];
  if (t < 64) nbs[t] = (t < nv) ? nbr[(size_t)g*KNB + t] : -1;
  if (t < 192) w1p[t] = w1[64*64 + t];
  else         b1s[t - 192] = b1[t - 192];
  __syncthreads();
  if (t < 64) {
    int ci = cloud*NPC + idx[g];
    float cxx = pos[3*ci], cyy = pos[3*ci+1], czz = pos[3*ci+2];
    int j = nbs[t];
    float r0 = 0.f, r1 = 0.f, r2 = 0.f;
    if (t < nv && j >= 0) {
      r0 = pos[3*j]   - cxx;
      r1 = pos[3*j+1] - cyy;
      r2 = pos[3*j+2] - czz;
    }
    rel[t][0] = r0; rel[t][1] = r1; rel[t][2] = r2;
  }
  {
    int row = t >> 2, part = t & 3;
    int j = nbs[row];
    uint4 v0 = make_uint4(0,0,0,0), v1 = make_uint4(0,0,0,0);
    if (row < nv && j >= 0) {
      const uint4* src = (const uint4*)(y + (size_t)j*64);
      v0 = src[part*2]; v1 = src[part*2 + 1];
    }
    *(uint4*)&YH[row][part*16]     = v0;
    *(uint4*)&YH[row][part*16 + 8] = v1;
  }
#pragma unroll
  for (int k = 0; k < 4; ++k) {
    int l = t + 256*k;             // 1024 uint4 total
    int row = l >> 3, part = l & 7;
    *(uint4*)&WT[row][part*8] = ((const uint4*)w2t)[l];
  }
  __syncthreads();
  {
    int s = t >> 2, c0 = (t & 3) << 4;
    float rx = rel[s][0], ry = rel[s][1], rz = rel[s][2];
#pragma unroll
    for (int c = 0; c < 16; ++c) {
      int cc = c0 + c;
      float v = bf2f(YH[s][cc]) + rx*w1p[cc] + ry*w1p[64+cc] + rz*w1p[128+cc] + b1s[cc];
      v = fmaxf(v, 0.f);
      YH[s][cc] = f2bf(v);
    }
  }
  __syncthreads();
  const int wv = t >> 6, lane = t & 63;
  const int arow = lane & 15, agrp = lane >> 4;
  const int col0 = wv << 5;
  f32x4 acc[4][2];
#pragma unroll
  for (int mt = 0; mt < 4; ++mt)
#pragma unroll
    for (int nt = 0; nt < 2; ++nt) {
      f32x4 z = {0.f, 0.f, 0.f, 0.f};
      acc[mt][nt] = z;
    }
#pragma unroll
  for (int kk = 0; kk < 2; ++kk) {
    short8 a[4], bm[2];
#pragma unroll
    for (int mt = 0; mt < 4; ++mt)
      a[mt] = *(const short8*)&YH[mt*16 + arow][kk*32 + agrp*8];
#pragma unroll
    for (int nt = 0; nt < 2; ++nt)
      bm[nt] = *(const short8*)&WT[col0 + nt*16 + arow][kk*32 + agrp*8];
#pragma unroll
    for (int mt = 0; mt < 4; ++mt)
#pragma unroll
      for (int nt = 0; nt < 2; ++nt)
        acc[mt][nt] = __builtin_amdgcn_mfma_f32_16x16x32_bf16(a[mt], bm[nt], acc[mt][nt], 0, 0, 0);
  }
  float p0 = -__builtin_inff(), p1 = -__builtin_inff();
#pragma unroll
  for (int mt = 0; mt < 4; ++mt) {
#pragma unroll
    for (int r = 0; r < 4; ++r) {
      int slot = mt*16 + agrp*4 + r;
      if (slot < nv) {
        p0 = fmaxf(p0, acc[mt][0][r]);
        p1 = fmaxf(p1, acc[mt][1][r]);
      }
    }
  }
  p0 = fmaxf(p0, __shfl_xor(p0, 16, 64));
  p0 = fmaxf(p0, __shfl_xor(p0, 32, 64));
  p1 = fmaxf(p1, __shfl_xor(p1, 16, 64));
  p1 = fmaxf(p1, __shfl_xor(p1, 32, 64));
  if (lane < 16) {
    int c = col0 + lane;
    out[(size_t)g*128 + c]      = (nv > 0) ? p0 + b2[c]      : 0.f;
    out[(size_t)g*128 + c + 16] = (nv > 0) ? p1 + b2[c + 16] : 0.f;
  }
}

// ---------------------------------------------------------------- launch
extern "C" void kernel_launch(void* const* d_in, const int* in_sizes, int n_in,
                              void* d_out, int out_size, void* d_ws, size_t ws_size,
                              hipStream_t stream) {
  const float* x   = (const float*)d_in[0];
  const float* pos = (const float*)d_in[1];
  // d_in[2] (batch) unused: layout is known (repeat arange(16), 4096 each)
  const float* W1  = (const float*)d_in[3];
  const float* b1  = (const float*)d_in[4];
  const float* W2  = (const float*)d_in[5];
  const float* b2  = (const float*)d_in[6];

  float* out       = (float*)d_out;                    // [16384,128]
  float* pos_out   = out + (size_t)NB*MPC*128;         // [16384,3]
  float* batch_out = pos_out + (size_t)NB*MPC*3;       // [16384]

  char* ws = (char*)d_ws;
  int* idx    = (int*)(ws);                                    // 64 KB
  int* nvalid = (int*)(ws + 65536);                            // 64 KB
  int* nbr    = (int*)(ws + 131072);                           // 4 MB
  u16* w2t    = (u16*)(ws + 131072 + 4194304);                 // 16 KB
  u16* y      = (u16*)(ws + 131072 + 4194304 + 16384);         // 8 MB

  fused_kernel<<<NB + 1024 + 1, 512, 0, stream>>>(pos, x, W1, W2, idx, pos_out,
                                                  batch_out, y, w2t);
  nbr_kernel <<<4096,  256, 0, stream>>>(pos, idx, nbr, nvalid);
  conv_kernel<<<16384, 256, 0, stream>>>(pos, idx, nbr, nvalid, y, w2t, W1, b1, b2, out);
}

// Round 18
// 833.755 us; speedup vs baseline: 1.2957x; 1.2957x over previous
//
#include <hip/hip_runtime.h>

#define NB   16
#define NPC  4096
#define MPC  1024
#define KNB  64
#define FIN  64
#define CAP  448   // candidate capacity per centroid (mean ~137, +26 sigma)

typedef unsigned short u16;
typedef unsigned int   u32;
typedef unsigned long long u64;
typedef __attribute__((ext_vector_type(8))) short short8;
typedef __attribute__((ext_vector_type(4))) float f32x4;

__device__ __forceinline__ u16 f2bf(float f) {
  u32 u = __float_as_uint(f);
  u = u + 0x7fffu + ((u >> 16) & 1u);
  return (u16)(u >> 16);
}
__device__ __forceinline__ float bf2f(u16 b) {
  return __uint_as_float(((u32)b) << 16);
}
__device__ __forceinline__ u32 umax2(u32 a, u32 b) { return a > b ? a : b; }

// ---- DPP wave reduces (VALU pipe). bound_ctrl=false => invalid/masked
// lanes keep old; compiler inserts mandatory DPP hazard waits (raw asm
// faulted in R2). row_shr moves values toward HIGHER lanes (R3-verified).
#define DPP64_MAX(best, ctrl, rmask) do { \
  u32 _lo = (u32)(best), _hi = (u32)((best) >> 32); \
  u32 _olo = (u32)__builtin_amdgcn_update_dpp((int)_lo, (int)_lo, (ctrl), (rmask), 0xf, false); \
  u32 _ohi = (u32)__builtin_amdgcn_update_dpp((int)_hi, (int)_hi, (ctrl), (rmask), 0xf, false); \
  u64 _o = ((u64)_ohi << 32) | _olo; \
  (best) = _o > (best) ? _o : (best); \
} while (0)

__device__ __forceinline__ u32 wave_max_u32(u32 x) {
  u32 t;
  t = (u32)__builtin_amdgcn_update_dpp((int)x, (int)x, 0x111, 0xf, 0xf, false); x = x > t ? x : t;
  t = (u32)__builtin_amdgcn_update_dpp((int)x, (int)x, 0x112, 0xf, 0xf, false); x = x > t ? x : t;
  t = (u32)__builtin_amdgcn_update_dpp((int)x, (int)x, 0x114, 0xf, 0xf, false); x = x > t ? x : t;
  t = (u32)__builtin_amdgcn_update_dpp((int)x, (int)x, 0x118, 0xf, 0xf, false); x = x > t ? x : t;
  t = (u32)__builtin_amdgcn_update_dpp((int)x, (int)x, 0x142, 0xa, 0xf, false); x = x > t ? x : t;
  t = (u32)__builtin_amdgcn_update_dpp((int)x, (int)x, 0x143, 0xc, 0xf, false); x = x > t ? x : t;
  return x;
}

struct FpsLDS {
  float4 sxyz[NPC];     // packed coords: 1 ds_read_b128 per centroid fetch
  u64 swave[2][8];
  int sidx[MPC];
};
struct YLDS { float xs[64][68]; float ws[64][68]; };
union FusedLDS { FpsLDS f; YLDS g; char pad[86016]; };  // 84KB => 1 block/CU
                                                        // (fps CUs exclusive)

// ---------------------------------------------------------------- fused FPS + y + w2t
// Blocks 0..15: FPS (R16-proven structure — best measured: 632 us).
//   Selection: 8 ballots + all-scalar first-r/ctz pick (SALU pipe).
//   Bit-exact: V is the wave max of mind bits (floats >= 0 => u32 order
//   == float order); smallest global index among matches == smallest r
//   with nonzero ballot (r*512 dominates t), then ctz(mask) -> smallest
//   lane. Cross-wave (V<<32)|~idx u64-max tie-break. vmax uses a
//   balanced u32-max tree (order-independent pure max => bit-exact).
// Blocks 16..1039: y = x @ W1[:64]. Block 1040: W2 -> bf16 transposed.
__global__ __launch_bounds__(512)
void fused_kernel(const float* __restrict__ pos, const float* __restrict__ x,
                  const float* __restrict__ w1, const float* __restrict__ w2,
                  int* __restrict__ idx_out, float* __restrict__ pos_out,
                  float* __restrict__ batch_out, u16* __restrict__ y,
                  u16* __restrict__ w2t) {
  __shared__ FusedLDS L;
  const int bid = blockIdx.x;
  const int t = threadIdx.x;
  if (bid < NB) {
    const int b = bid;
    const int w = t >> 6, lane = t & 63;
    const float* P = pos + (size_t)b * NPC * 3;
    for (int i = t; i < NPC; i += 512)
      L.f.sxyz[i] = make_float4(P[3*i+0], P[3*i+1], P[3*i+2], 0.f);
    for (int i = t; i < MPC; i += 512) batch_out[b*MPC + i] = (float)b;
    if (t == 0) L.f.sidx[0] = 0;
    __syncthreads();
    float px[8], py[8], pz[8], mind[8];
#pragma unroll
    for (int r = 0; r < 8; ++r) {
      float4 p = L.f.sxyz[t + (r << 9)];
      px[r] = p.x; py[r] = p.y; pz[r] = p.z;
      mind[r] = __builtin_inff();
    }
    int last = 0;
    for (int m = 1; m < MPC; ++m) {
      float4 c = L.f.sxyz[last];           // 1 ds_read_b128
#pragma unroll
      for (int r = 0; r < 8; ++r) {
        float dx = __fsub_rn(px[r], c.x);
        float dy = __fsub_rn(py[r], c.y);
        float dz = __fsub_rn(pz[r], c.z);
        float d2 = __fadd_rn(__fadd_rn(__fmul_rn(dx,dx), __fmul_rn(dy,dy)), __fmul_rn(dz,dz));
        mind[r] = fminf(mind[r], d2);
      }
      u32 q0 = __float_as_uint(mind[0]), q1 = __float_as_uint(mind[1]);
      u32 q2 = __float_as_uint(mind[2]), q3 = __float_as_uint(mind[3]);
      u32 q4 = __float_as_uint(mind[4]), q5 = __float_as_uint(mind[5]);
      u32 q6 = __float_as_uint(mind[6]), q7 = __float_as_uint(mind[7]);
      u32 vmax = umax2(umax2(umax2(q0,q1), umax2(q2,q3)),
                       umax2(umax2(q4,q5), umax2(q6,q7)));
      vmax = wave_max_u32(vmax);
      u32 V = (u32)__builtin_amdgcn_readlane((int)vmax, 63);
      // --- scalar argmin-index selection (R14-proven)
      u64 mk0 = __ballot(q0 == V);
      u64 mk1 = __ballot(q1 == V);
      u64 mk2 = __ballot(q2 == V);
      u64 mk3 = __ballot(q3 == V);
      u64 mk4 = __ballot(q4 == V);
      u64 mk5 = __ballot(q5 == V);
      u64 mk6 = __ballot(q6 == V);
      u64 mk7 = __ballot(q7 == V);
      u64 msel = mk7; u32 rsel = 7u;
      msel = mk6 ? mk6 : msel; rsel = mk6 ? 6u : rsel;
      msel = mk5 ? mk5 : msel; rsel = mk5 ? 5u : rsel;
      msel = mk4 ? mk4 : msel; rsel = mk4 ? 4u : rsel;
      msel = mk3 ? mk3 : msel; rsel = mk3 ? 3u : rsel;
      msel = mk2 ? mk2 : msel; rsel = mk2 ? 2u : rsel;
      msel = mk1 ? mk1 : msel; rsel = mk1 ? 1u : rsel;
      msel = mk0 ? mk0 : msel; rsel = mk0 ? 0u : rsel;
      u32 cand = (u32)(w << 6) + (u32)__builtin_ctzll(msel) + (rsel << 9);
      if (lane == 63) L.f.swave[m & 1][w] = ((u64)V << 32) | (u32)(~cand);
      __syncthreads();   // single barrier per step (parity double-buffer)
      u64 sv = 0;
      if (lane < 8) sv = L.f.swave[m & 1][lane];
      DPP64_MAX(sv, 0x111, 0xf);
      DPP64_MAX(sv, 0x112, 0xf);
      DPP64_MAX(sv, 0x114, 0xf);
      u32 lo = (u32)__builtin_amdgcn_readlane((int)(u32)sv, 7);
      last = (int)(~lo);
      if (t == 0) L.f.sidx[m] = last;     // LDS only — no vmem in the loop
    }
    __syncthreads();
    for (int i = t; i < MPC; i += 512) {
      int ii = L.f.sidx[i];
      idx_out[b*MPC + i] = ii;
      float4 p = L.f.sxyz[ii];
      size_t po = ((size_t)b*MPC + i)*3;
      pos_out[po+0] = p.x; pos_out[po+1] = p.y; pos_out[po+2] = p.z;
    }
  } else if (bid < NB + 1024) {
    const size_t row0 = (size_t)(bid - NB) * 64;
#pragma unroll
    for (int k = 0; k < 2; ++k) {
      int l4 = t + 512*k;              // 0..1023 float4 index
      int r = l4 >> 4, c4 = l4 & 15;
      *(float4*)&L.g.xs[r][c4*4] = *(const float4*)&x[(row0 + r)*64 + c4*4];
      *(float4*)&L.g.ws[r][c4*4] = *(const float4*)&w1[r*64 + c4*4];
    }
    __syncthreads();
    const int r = t >> 3, c0 = (t & 7) << 3;
    float acc[8];
#pragma unroll
    for (int i = 0; i < 8; ++i) acc[i] = 0.f;
    for (int k = 0; k < 64; ++k) {
      float a = L.g.xs[r][k];
      float4 w0 = *(const float4*)&L.g.ws[k][c0];
      float4 w1v = *(const float4*)&L.g.ws[k][c0 + 4];
      acc[0] += a * w0.x; acc[1] += a * w0.y; acc[2] += a * w0.z; acc[3] += a * w0.w;
      acc[4] += a * w1v.x; acc[5] += a * w1v.y; acc[6] += a * w1v.z; acc[7] += a * w1v.w;
    }
    u32 u[4];
#pragma unroll
    for (int i = 0; i < 4; ++i)
      u[i] = (u32)f2bf(acc[2*i]) | ((u32)f2bf(acc[2*i+1]) << 16);
    *(uint4*)(y + ((row0 + r)*64 + c0)) = make_uint4(u[0], u[1], u[2], u[3]);
  } else {
    for (int i = t; i < 64*128; i += 512) {
      int k = i >> 7, c = i & 127;
      w2t[c*64 + k] = f2bf(w2[i]);
    }
  }
}

// ---------------------------------------------------------------- radius + top-64 neighbors
// (verbatim R9/R14 — proven)
__global__ __launch_bounds__(256)
void nbr_kernel(const float* __restrict__ pos, const int* __restrict__ idx,
                int* __restrict__ nbr, int* __restrict__ nvalid) {
  const int bid = blockIdx.x;
  const int sw = (bid & 7) * 512 + (bid >> 3);   // bijective XCD swizzle (4096 = 8*512)
  const int cloud = sw >> 8;
  const int mbase = (sw & 255) << 2;
  __shared__ float sx[NPC], sy[NPC], sz[NPC];
  __shared__ u64 cand[4][CAP];
  const float* P = pos + (size_t)cloud * NPC * 3;
  const int t = threadIdx.x;
  for (int i = t; i < NPC; i += 256) { sx[i]=P[3*i]; sy[i]=P[3*i+1]; sz[i]=P[3*i+2]; }
  __syncthreads();
  const int wv = t >> 6, lane = t & 63;
  const int m = mbase + wv;
  const int g = cloud * MPC + m;
  const int ci = idx[g];
  const float cx = sx[ci], cy = sy[ci], cz = sz[ci];
  const float R2 = 0.04000000059604644775f;      // (float)(0.2*0.2)
  const u64 ltmask = (lane == 0) ? 0ull : (~0ull >> (64 - lane));
  int base = 0;
  for (int i = 0; i < NPC/64; ++i) {
    int j = (i << 6) + lane;
    float dx = __fsub_rn(cx, sx[j]);
    float dy = __fsub_rn(cy, sy[j]);
    float dz = __fsub_rn(cz, sz[j]);
    float d2 = __fadd_rn(__fadd_rn(__fmul_rn(dx,dx), __fmul_rn(dy,dy)), __fmul_rn(dz,dz));
    bool in = d2 <= R2;
    u64 mk = __ballot(in);
    if (in) {
      int slot = base + (int)__popcll(mk & ltmask);
      if (slot < CAP)
        cand[wv][slot] = ((u64)__float_as_uint(d2) << 32) | (u32)j;
    }
    base += (int)__popcll(mk);
  }
  int cnt = base < CAP ? base : CAP;
  u64 mykey[7];
  int myrank[7];
#pragma unroll
  for (int u = 0; u < 7; ++u) {
    int s = lane + (u << 6);
    mykey[u] = (s < cnt) ? cand[wv][s] : ~0ull;
    myrank[u] = 0;
  }
  for (int jj = 0; jj < cnt; ++jj) {
    u64 kj = cand[wv][jj];
#pragma unroll
    for (int u = 0; u < 7; ++u) myrank[u] += (kj < mykey[u]) ? 1 : 0;
  }
#pragma unroll
  for (int u = 0; u < 7; ++u) {
    int s = lane + (u << 6);
    if (s < cnt && myrank[u] < KNB)
      nbr[(size_t)g*KNB + myrank[u]] = cloud*NPC + (int)(mykey[u] & 0xffffffffull);
  }
  if (lane == 0) nvalid[g] = cnt < KNB ? cnt : KNB;
}

// ---------------------------------------------------------------- PointNetConv (one block per centroid)
// (verbatim R9/R14 — proven)
__global__ __launch_bounds__(256)
void conv_kernel(const float* __restrict__ pos, const int* __restrict__ idx,
                 const int* __restrict__ nbr, const int* __restrict__ nvalid,
                 const u16* __restrict__ y, const u16* __restrict__ w2t,
                 const float* __restrict__ w1, const float* __restrict__ b1,
                 const float* __restrict__ b2, float* __restrict__ out) {
  const int bid = blockIdx.x;
  const int g = (bid & 7) * 2048 + (bid >> 3);   // bijective XCD swizzle (16384 = 8*2048)
  const int cloud = g >> 10;
  __shared__ u16 YH[64][72];     // y rows, then relu'd H1 in-place (same-thread RMW)
  __shared__ u16 WT[128][72];    // W2^T bf16
  __shared__ float rel[64][3];
  __shared__ int nbs[64];
  __shared__ float w1p[192];
  __shared__ float b1s[64];
  const int t = threadIdx.x;
  const int nv = nvalid[g];
  if (t < 64) nbs[t] = (t < nv) ? nbr[(size_t)g*KNB + t] : -1;
  if (t < 192) w1p[t] = w1[64*64 + t];
  else         b1s[t - 192] = b1[t - 192];
  __syncthreads();
  if (t < 64) {
    int ci = cloud*NPC + idx[g];
    float cxx = pos[3*ci], cyy = pos[3*ci+1], czz = pos[3*ci+2];
    int j = nbs[t];
    float r0 = 0.f, r1 = 0.f, r2 = 0.f;
    if (t < nv && j >= 0) {
      r0 = pos[3*j]   - cxx;
      r1 = pos[3*j+1] - cyy;
      r2 = pos[3*j+2] - czz;
    }
    rel[t][0] = r0; rel[t][1] = r1; rel[t][2] = r2;
  }
  {
    int row = t >> 2, part = t & 3;
    int j = nbs[row];
    uint4 v0 = make_uint4(0,0,0,0), v1 = make_uint4(0,0,0,0);
    if (row < nv && j >= 0) {
      const uint4* src = (const uint4*)(y + (size_t)j*64);
      v0 = src[part*2]; v1 = src[part*2 + 1];
    }
    *(uint4*)&YH[row][part*16]     = v0;
    *(uint4*)&YH[row][part*16 + 8] = v1;
  }
#pragma unroll
  for (int k = 0; k < 4; ++k) {
    int l = t + 256*k;             // 1024 uint4 total
    int row = l >> 3, part = l & 7;
    *(uint4*)&WT[row][part*8] = ((const uint4*)w2t)[l];
  }
  __syncthreads();
  {
    int s = t >> 2, c0 = (t & 3) << 4;
    float rx = rel[s][0], ry = rel[s][1], rz = rel[s][2];
#pragma unroll
    for (int c = 0; c < 16; ++c) {
      int cc = c0 + c;
      float v = bf2f(YH[s][cc]) + rx*w1p[cc] + ry*w1p[64+cc] + rz*w1p[128+cc] + b1s[cc];
      v = fmaxf(v, 0.f);
      YH[s][cc] = f2bf(v);
    }
  }
  __syncthreads();
  const int wv = t >> 6, lane = t & 63;
  const int arow = lane & 15, agrp = lane >> 4;
  const int col0 = wv << 5;
  f32x4 acc[4][2];
#pragma unroll
  for (int mt = 0; mt < 4; ++mt)
#pragma unroll
    for (int nt = 0; nt < 2; ++nt) {
      f32x4 z = {0.f, 0.f, 0.f, 0.f};
      acc[mt][nt] = z;
    }
#pragma unroll
  for (int kk = 0; kk < 2; ++kk) {
    short8 a[4], bm[2];
#pragma unroll
    for (int mt = 0; mt < 4; ++mt)
      a[mt] = *(const short8*)&YH[mt*16 + arow][kk*32 + agrp*8];
#pragma unroll
    for (int nt = 0; nt < 2; ++nt)
      bm[nt] = *(const short8*)&WT[col0 + nt*16 + arow][kk*32 + agrp*8];
#pragma unroll
    for (int mt = 0; mt < 4; ++mt)
#pragma unroll
      for (int nt = 0; nt < 2; ++nt)
        acc[mt][nt] = __builtin_amdgcn_mfma_f32_16x16x32_bf16(a[mt], bm[nt], acc[mt][nt], 0, 0, 0);
  }
  float p0 = -__builtin_inff(), p1 = -__builtin_inff();
#pragma unroll
  for (int mt = 0; mt < 4; ++mt) {
#pragma unroll
    for (int r = 0; r < 4; ++r) {
      int slot = mt*16 + agrp*4 + r;
      if (slot < nv) {
        p0 = fmaxf(p0, acc[mt][0][r]);
        p1 = fmaxf(p1, acc[mt][1][r]);
      }
    }
  }
  p0 = fmaxf(p0, __shfl_xor(p0, 16, 64));
  p0 = fmaxf(p0, __shfl_xor(p0, 32, 64));
  p1 = fmaxf(p1, __shfl_xor(p1, 16, 64));
  p1 = fmaxf(p1, __shfl_xor(p1, 32, 64));
  if (lane < 16) {
    int c = col0 + lane;
    out[(size_t)g*128 + c]      = (nv > 0) ? p0 + b2[c]      : 0.f;
    out[(size_t)g*128 + c + 16] = (nv > 0) ? p1 + b2[c + 16] : 0.f;
  }
}

// ---------------------------------------------------------------- launch
extern "C" void kernel_launch(void* const* d_in, const int* in_sizes, int n_in,
                              void* d_out, int out_size, void* d_ws, size_t ws_size,
                              hipStream_t stream) {
  const float* x   = (const float*)d_in[0];
  const float* pos = (const float*)d_in[1];
  // d_in[2] (batch) unused: layout is known (repeat arange(16), 4096 each)
  const float* W1  = (const float*)d_in[3];
  const float* b1  = (const float*)d_in[4];
  const float* W2  = (const float*)d_in[5];
  const float* b2  = (const float*)d_in[6];

  float* out       = (float*)d_out;                    // [16384,128]
  float* pos_out   = out + (size_t)NB*MPC*128;         // [16384,3]
  float* batch_out = pos_out + (size_t)NB*MPC*3;       // [16384]

  char* ws = (char*)d_ws;
  int* idx    = (int*)(ws);                                    // 64 KB
  int* nvalid = (int*)(ws + 65536);                            // 64 KB
  int* nbr    = (int*)(ws + 131072);                           // 4 MB
  u16* w2t    = (u16*)(ws + 131072 + 4194304);                 // 16 KB
  u16* y      = (u16*)(ws + 131072 + 4194304 + 16384);         // 8 MB

  fused_kernel<<<NB + 1024 + 1, 512, 0, stream>>>(pos, x, W1, W2, idx, pos_out,
                                                  batch_out, y, w2t);
  nbr_kernel <<<4096,  256, 0, stream>>>(pos, idx, nbr, nvalid);
  conv_kernel<<<16384, 256, 0, stream>>>(pos, idx, nbr, nvalid, y, w2t, W1, b1, b2, out);
}